// Round 1
// 230.126 us; speedup vs baseline: 1.1551x; 1.1551x over previous
//
#include <hip/hip_runtime.h>
#include <hip/hip_fp16.h>

// GAT conv: N=100000, E=1.6M, IN_C=128, OUT_C=32, HEADS=4 (OC=128)
// Round 8:
//  - Fill rewritten as deterministic per-block LDS counting sort:
//    196 blocks x 8192 edges, LDS histogram (1563 buckets) -> block scan ->
//    LDS scatter -> ONE coalesced 32KB stream-out per block.
//    Kills all 1.6M global atomics (k_main was latency-bound at 90.9us with
//    MfmaUtil 1.5% / VALUBusy 3.9% / HBM 16%) and the ~55MB of 4B-scatter
//    write amplification (WRITE_SIZE 84.4MB vs 29MB contiguous payload).
//    Also removes the CAP-overflow drop hazard: per-bucket counts are exact.
//  - GEMM split back into its own kernel (both pieces now streaming;
//    fusion only paid when fill was atomic-latency-bound).
//  - k_tile ingest: per-bucket runs located via starts[fb][b] table,
//    4-wave scan over FB=196 counts + LDS binary-search gather.
//    Downstream row-sort/softmax/aggregate unchanged.

constexpr float NEG_SLOPE = 0.2f;
constexpr int TILE_ROWS = 64;       // rows per bucket (row>>6)
constexpr int SLAB = 2048;          // max edges per bucket staged in LDS
constexpr int EPB = 8192;           // edges per fill block
constexpr int NB_PAD = 2048;        // padded bucket count for block scan
constexpr int FBMAX = 256;          // k_tile ingest supports up to 256 fill blocks

typedef __attribute__((ext_vector_type(8))) short short8;
typedef __attribute__((ext_vector_type(4))) float f32x4;

__device__ inline short f2bf(float f) {
    unsigned u = __float_as_uint(f);
    return (short)((u + 0x7fffu + ((u >> 16) & 1u)) >> 16);
}

// Build augmented bf16 weight Wa[144][128]:
//   rows 0..127  = W (cast)
//   rows 128+h   = wl[h,:] = sum_c attl[h,c] * W[h*32+c,:]
//   rows 132+h   = wr[h,:]
//   rows 136..143 = 0
__global__ __launch_bounds__(256) void k_prep(const float* __restrict__ W,
                                              const float* __restrict__ attl,
                                              const float* __restrict__ attr,
                                              short* __restrict__ Wa) {
    int blk = blockIdx.x;
    int t = threadIdx.x;
    if (blk < 64) {
        int i = blk * 256 + t;
        Wa[i] = f2bf(W[i]);
    } else if (blk == 64) {
        for (int s = t; s < 1024; s += 256) {
            int which = s >> 9;          // 0 = l, 1 = r
            int h = (s >> 7) & 3;
            int k = s & 127;
            const float* att = which ? attr : attl;
            float acc = 0.f;
#pragma unroll 8
            for (int c = 0; c < 32; ++c)
                acc += att[h * 32 + c] * W[(h * 32 + c) * 128 + k];
            Wa[(128 + which * 4 + h) * 128 + k] = f2bf(acc);
        }
    } else {
        int i = (blk - 65) * 256 + t;    // 1024 zero shorts (rows 136..143)
        if (i < 1024) Wa[136 * 128 + i] = 0;
    }
}

// Per-block counting sort of 8192 edges by row-bucket. No global atomics.
// Output: slab[fb*EPB + starts[fb][b] .. ) holds bucket b's run for block fb;
// starts[fb][NB] = edge count of block fb (exclusive-scan sentinel).
__global__ __launch_bounds__(512) void k_fill(const int* __restrict__ ei,
                                              unsigned int* __restrict__ slab,
                                              int* __restrict__ starts,
                                              int E, int NB) {
    __shared__ int s_hist[NB_PAD];            // counts -> exclusive bases (8 KB)
    __shared__ int s_cur[NB_PAD];             // scatter cursors (8 KB)
    __shared__ unsigned int s_stage[EPB];     // 32 KB
    __shared__ int s_wsum[8];

    int fb = blockIdx.x;
    int t = threadIdx.x;
    int lane = t & 63, wv = t >> 6;
    int e0 = fb * EPB;
    int ecnt = min(EPB, E - e0);
    bool full = (ecnt == EPB) && ((E & 3) == 0);

    for (int i = t; i < NB_PAD; i += 512) s_hist[i] = 0;
    __syncthreads();

    const int* rows = ei;
    const int* cols = ei + E;

    // pass 1: LDS histogram over buckets
    if (full) {
        const int4* r4 = (const int4*)rows + (e0 >> 2);
#pragma unroll
        for (int k = 0; k < 4; ++k) {
            int4 ra = r4[k * 512 + t];
            atomicAdd(&s_hist[ra.x >> 6], 1);
            atomicAdd(&s_hist[ra.y >> 6], 1);
            atomicAdd(&s_hist[ra.z >> 6], 1);
            atomicAdd(&s_hist[ra.w >> 6], 1);
        }
    } else {
        for (int j = t; j < ecnt; j += 512)
            atomicAdd(&s_hist[rows[e0 + j] >> 6], 1);
    }
    __syncthreads();

    // block-wide exclusive scan of s_hist[0..NB_PAD): 4 buckets/thread,
    // wave shfl scan, serial scan of 8 wave totals.
    int b0 = t * 4;
    int c0 = s_hist[b0], c1 = s_hist[b0 + 1], c2 = s_hist[b0 + 2], c3 = s_hist[b0 + 3];
    int p = c0 + c1 + c2 + c3;
    int v = p;
#pragma unroll
    for (int off = 1; off < 64; off <<= 1) {
        int u = __shfl_up(v, off);
        if (lane >= off) v += u;
    }
    if (lane == 63) s_wsum[wv] = v;
    __syncthreads();
    if (t == 0) {
        int run = 0;
#pragma unroll
        for (int w = 0; w < 8; ++w) { int tmp = s_wsum[w]; s_wsum[w] = run; run += tmp; }
    }
    __syncthreads();
    int base = s_wsum[wv] + (v - p);          // exclusive prefix for bucket b0
    int e1 = base + c0, e2 = e1 + c1, e3 = e2 + c2;
    s_hist[b0] = base; s_hist[b0 + 1] = e1; s_hist[b0 + 2] = e2; s_hist[b0 + 3] = e3;
    s_cur[b0] = base;  s_cur[b0 + 1] = e1;  s_cur[b0 + 2] = e2;  s_cur[b0 + 3] = e3;
    size_t sb = (size_t)fb * (NB + 1);
    if (b0 + 0 <= NB) starts[sb + b0 + 0] = base;
    if (b0 + 1 <= NB) starts[sb + b0 + 1] = e1;
    if (b0 + 2 <= NB) starts[sb + b0 + 2] = e2;
    if (b0 + 3 <= NB) starts[sb + b0 + 3] = e3;
    __syncthreads();

    // pass 2: scatter edges into LDS stage, grouped by bucket
    if (full) {
        const int4* r4 = (const int4*)rows + (e0 >> 2);
        const int4* c4 = (const int4*)cols + (e0 >> 2);
#pragma unroll
        for (int k = 0; k < 4; ++k) {
            int4 ra = r4[k * 512 + t];
            int4 ca = c4[k * 512 + t];
            int pos;
            pos = atomicAdd(&s_cur[ra.x >> 6], 1);
            s_stage[pos] = ((unsigned int)ca.x << 6) | (unsigned int)(ra.x & 63);
            pos = atomicAdd(&s_cur[ra.y >> 6], 1);
            s_stage[pos] = ((unsigned int)ca.y << 6) | (unsigned int)(ra.y & 63);
            pos = atomicAdd(&s_cur[ra.z >> 6], 1);
            s_stage[pos] = ((unsigned int)ca.z << 6) | (unsigned int)(ra.z & 63);
            pos = atomicAdd(&s_cur[ra.w >> 6], 1);
            s_stage[pos] = ((unsigned int)ca.w << 6) | (unsigned int)(ra.w & 63);
        }
    } else {
        for (int j = t; j < ecnt; j += 512) {
            int rr = rows[e0 + j], cc = cols[e0 + j];
            int pos = atomicAdd(&s_cur[rr >> 6], 1);
            s_stage[pos] = ((unsigned int)cc << 6) | (unsigned int)(rr & 63);
        }
    }
    __syncthreads();

    // coalesced stream-out of the block's sorted region
    uint4* dst = (uint4*)(slab + (size_t)fb * EPB);
    const uint4* src = (const uint4*)s_stage;
    int n4 = (ecnt + 3) >> 2;
    for (int i = t; i < n4; i += 512) dst[i] = src[i];
}

// MFMA GEMM: wave computes 16 nodes x 144 couts (128 proj + 8 l/r columns).
__global__ __launch_bounds__(256) void k_gemm(const float* __restrict__ x,
                                              const short* __restrict__ Wa,
                                              __half* __restrict__ xph,
                                              float* __restrict__ l,
                                              float* __restrict__ r,
                                              int N) {
    int t = threadIdx.x;
    int wave = t >> 6, lane = t & 63;
    int li = lane & 15, quad = lane >> 4;
    int base = blockIdx.x * 64 + wave * 16;

    f32x4 acc[9];
#pragma unroll
    for (int nt = 0; nt < 9; ++nt) acc[nt] = (f32x4){0.f, 0.f, 0.f, 0.f};

    int anode = base + li;
    bool avalid = anode < N;
    const float4* x4 = (const float4*)x;
    const short8* wb8 = (const short8*)Wa;

#pragma unroll
    for (int kc = 0; kc < 4; ++kc) {
        float4 p0 = make_float4(0.f, 0.f, 0.f, 0.f), p1 = p0;
        if (avalid) {
            p0 = x4[(size_t)anode * 32 + kc * 8 + quad * 2];
            p1 = x4[(size_t)anode * 32 + kc * 8 + quad * 2 + 1];
        }
        short8 a;
        a[0] = f2bf(p0.x); a[1] = f2bf(p0.y); a[2] = f2bf(p0.z); a[3] = f2bf(p0.w);
        a[4] = f2bf(p1.x); a[5] = f2bf(p1.y); a[6] = f2bf(p1.z); a[7] = f2bf(p1.w);
#pragma unroll
        for (int nt = 0; nt < 9; ++nt) {
            short8 b = wb8[(nt * 16 + li) * 16 + kc * 4 + quad];
            acc[nt] = __builtin_amdgcn_mfma_f32_16x16x32_bf16(a, b, acc[nt], 0, 0, 0);
        }
    }

#pragma unroll
    for (int j = 0; j < 4; ++j) {
        int node = base + quad * 4 + j;
        if (node >= N) continue;
#pragma unroll
        for (int nt = 0; nt < 8; ++nt)
            xph[(size_t)node * 128 + nt * 16 + li] = __float2half(acc[nt][j]);
        // augmented columns: li<4 -> l head li; li in [4,8) -> r head li-4
        if (li < 4)      l[node * 4 + li] = acc[8][j];
        else if (li < 8) r[node * 4 + li - 4] = acc[8][j];
    }
}

// One block per bucket, 512 threads = 8 waves.
__global__ __launch_bounds__(512) void k_tile(const int* __restrict__ starts,
                                              const unsigned int* __restrict__ slab,
                                              const float* __restrict__ l,
                                              const float* __restrict__ r,
                                              const __half* __restrict__ xph,
                                              const float* __restrict__ bias,
                                              float* __restrict__ out,
                                              int N, int NB, int FB) {
    __shared__ unsigned int s_packed[SLAB];   // 8 KB
    __shared__ int s_col[SLAB];               // 8 KB
    __shared__ int s_start[TILE_ROWS + 1];
    __shared__ int s_cursor[TILE_ROWS];
    __shared__ int s_cnt[TILE_ROWS];
    __shared__ int s_fbase[FBMAX];            // within-block run start per fill block
    __shared__ int s_foff[FBMAX + 1];         // run placement in s_packed
    __shared__ int s_w4[4];

    int b = blockIdx.x;
    int base = b * TILE_ROWS;
    int t = threadIdx.x;
    int lane = t & 63, wv = t >> 6;

    if (t < TILE_ROWS) s_cnt[t] = 0;

    // per-fill-block run start/count for this bucket
    int myc = 0;
    if (t < FB) {
        const int* sp = starts + (size_t)t * (NB + 1) + b;
        int a0 = sp[0], a1 = sp[1];
        s_fbase[t] = a0;
        myc = a1 - a0;
    }
    // exclusive scan of run counts over first 4 waves
    int v = 0;
    if (t < 256) {
        v = myc;                               // t >= FB contributes 0
#pragma unroll
        for (int off = 1; off < 64; off <<= 1) {
            int u = __shfl_up(v, off);
            if (lane >= off) v += u;
        }
        if (lane == 63) s_w4[wv] = v;
    }
    __syncthreads();
    if (t == 0) {
        int run = 0;
#pragma unroll
        for (int w = 0; w < 4; ++w) { int tmp = s_w4[w]; s_w4[w] = run; run += tmp; }
        s_foff[0] = 0;
    }
    __syncthreads();
    if (t < 256) s_foff[t + 1] = v + s_w4[wv];
    __syncthreads();
    int tot = s_foff[FB];
    if (tot > SLAB) tot = SLAB;

    // gather runs into s_packed (binary search for owning fill block)
    for (int i = t; i < tot; i += 512) {
        int lo = 0, hi = FB;
        while (hi - lo > 1) {
            int mid = (lo + hi) >> 1;
            if (s_foff[mid] <= i) lo = mid; else hi = mid;
        }
        unsigned int p = slab[(size_t)lo * EPB + s_fbase[lo] + (i - s_foff[lo])];
        s_packed[i] = p;
        atomicAdd(&s_cnt[p & 63], 1);
    }
    __syncthreads();

    // counting sort by row within the bucket
    if (t < 64) {
        int c = s_cnt[t];
        int vv = c;
#pragma unroll
        for (int off = 1; off < 64; off <<= 1) {
            int u = __shfl_up(vv, off);
            if (t >= off) vv += u;
        }
        s_start[t + 1] = vv;
        if (t == 0) s_start[0] = 0;
        s_cursor[t] = vv - c;   // exclusive
    }
    __syncthreads();
    for (int i = t; i < tot; i += 512) {
        unsigned int p = s_packed[i];
        int pos = atomicAdd(&s_cursor[p & 63], 1);
        s_col[pos] = (int)(p >> 6);
    }
    __syncthreads();

    int quarter = lane >> 4;   // edge slot within wave (4 in flight)
    int li = lane & 15;        // channel block: fp16 chans 8li..8li+7
    int h = li >> 2;           // head of this channel block
    int rows = min(TILE_ROWS, N - base);
    const float4* xp4g = (const float4*)xph;  // 16B = 8 halves

    float4 b0 = ((const float4*)bias)[2 * li];
    float4 b1 = ((const float4*)bias)[2 * li + 1];

    for (int rl = wv; rl < rows; rl += 8) {
        int s0 = s_start[rl], s1 = s_start[rl + 1];
        float lh = l[(base + rl) * 4 + h];
        float a0 = 0.f, a1 = 0.f, a2 = 0.f, a3 = 0.f;
        float a4 = 0.f, a5 = 0.f, a6 = 0.f, a7 = 0.f;
        float dsum = 0.f;
#pragma unroll 2
        for (int i = s0 + quarter; i < s1; i += 4) {
            int col = s_col[i];
            float rh = r[col * 4 + h];
            float a = lh + rh;
            a = a >= 0.f ? a : NEG_SLOPE * a;
            float w = __expf(a);
            float4 raw = xp4g[(size_t)col * 16 + li];
            __half2* hp = (__half2*)&raw;
            float2 f0 = __half22float2(hp[0]);
            float2 f1 = __half22float2(hp[1]);
            float2 f2 = __half22float2(hp[2]);
            float2 f3 = __half22float2(hp[3]);
            a0 += w * f0.x; a1 += w * f0.y;
            a2 += w * f1.x; a3 += w * f1.y;
            a4 += w * f2.x; a5 += w * f2.y;
            a6 += w * f3.x; a7 += w * f3.y;
            dsum += w;
        }
        a0 += __shfl_xor(a0, 16); a0 += __shfl_xor(a0, 32);
        a1 += __shfl_xor(a1, 16); a1 += __shfl_xor(a1, 32);
        a2 += __shfl_xor(a2, 16); a2 += __shfl_xor(a2, 32);
        a3 += __shfl_xor(a3, 16); a3 += __shfl_xor(a3, 32);
        a4 += __shfl_xor(a4, 16); a4 += __shfl_xor(a4, 32);
        a5 += __shfl_xor(a5, 16); a5 += __shfl_xor(a5, 32);
        a6 += __shfl_xor(a6, 16); a6 += __shfl_xor(a6, 32);
        a7 += __shfl_xor(a7, 16); a7 += __shfl_xor(a7, 32);
        dsum += __shfl_xor(dsum, 16); dsum += __shfl_xor(dsum, 32);
        if (quarter == 0) {
            float inv = 1.f / (dsum + 1e-16f);
            float4 o0, o1;
            o0.x = a0 * inv + b0.x; o0.y = a1 * inv + b0.y;
            o0.z = a2 * inv + b0.z; o0.w = a3 * inv + b0.w;
            o1.x = a4 * inv + b1.x; o1.y = a5 * inv + b1.y;
            o1.z = a6 * inv + b1.z; o1.w = a7 * inv + b1.w;
            ((float4*)out)[(size_t)(base + rl) * 32 + 2 * li] = o0;
            ((float4*)out)[(size_t)(base + rl) * 32 + 2 * li + 1] = o1;
        }
    }
}

extern "C" void kernel_launch(void* const* d_in, const int* in_sizes, int n_in,
                              void* d_out, int out_size, void* d_ws, size_t ws_size,
                              hipStream_t stream) {
    const float* x    = (const float*)d_in[0];
    const int*   ei   = (const int*)d_in[1];
    const float* W    = (const float*)d_in[2];
    const float* attl = (const float*)d_in[3];
    const float* attr = (const float*)d_in[4];
    const float* bias = (const float*)d_in[5];
    int N = in_sizes[0] / 128;
    int E = in_sizes[1] / 2;
    int NB = (N + TILE_ROWS - 1) / TILE_ROWS;
    int FB = (E + EPB - 1) / EPB;    // 196 for E=1.6M (k_tile supports <= FBMAX)

    char* ws = (char*)d_ws;
    __half* xph = (__half*)ws;   ws += (size_t)N * 128 * 2;          // 25.6 MB
    float* l    = (float*)ws;    ws += (size_t)N * 4 * 4;
    float* r    = (float*)ws;    ws += (size_t)N * 4 * 4;
    short* Wa   = (short*)ws;    ws += 144 * 128 * 2;
    int* starts = (int*)ws;      ws += (size_t)FB * (NB + 1) * 4;    // 1.23 MB
    unsigned int* slab = (unsigned int*)ws; ws += (size_t)FB * EPB * 4; // 6.42 MB

    float* out = (float*)d_out;
    int GB = (N + 63) / 64;

    k_prep<<<69, 256, 0, stream>>>(W, attl, attr, Wa);
    k_fill<<<FB, 512, 0, stream>>>(ei, slab, starts, E, NB);
    k_gemm<<<GB, 256, 0, stream>>>(x, Wa, xph, l, r, N);
    k_tile<<<NB, 512, 0, stream>>>(starts, slab, l, r, xph, bias, out, N, NB, FB);
}

// Round 2
// 224.581 us; speedup vs baseline: 1.1837x; 1.0247x over previous
//
#include <hip/hip_runtime.h>
#include <hip/hip_fp16.h>

// GAT conv: N=100000, E=1.6M, IN_C=128, OUT_C=32, HEADS=4 (OC=128)
// Round 9:
//  - k_tile: alpha hoisted out of the gather loop. The col-scatter pass now
//    computes all 4 head weights per edge (one float4 r read per edge),
//    stores them fp16 in LDS aligned with s_col, and accumulates exact
//    per-(row,head) denominators via LDS atomics. PV loop is now pure
//    {ds_read col/w, gather, 8 FMA}, 2-deep software-pipelined (two gathers
//    in flight per slot -> 8 per wave); dsum shuffle-reduce eliminated.
//    (Was: dependent r-load + leaky + __expf per edge inside the latency
//    chain; VALUBusy 44%, 84us, latency-bound.)
//  - k_gemm: Wa (36.8KB, just over 32KB L1 -> thrash) now staged once per
//    block into LDS with +16B row pad (272B stride hits the ds_read_b128
//    bank floor); 512-thread blocks (128 nodes) halve staging overhead.
//  - k_fill unchanged (deterministic counting sort, no global atomics).

constexpr float NEG_SLOPE = 0.2f;
constexpr int TILE_ROWS = 64;       // rows per bucket (row>>6)
constexpr int SLAB = 2048;          // max edges per bucket staged in LDS
constexpr int EPB = 8192;           // edges per fill block
constexpr int NB_PAD = 2048;        // padded bucket count for block scan
constexpr int FBMAX = 256;          // k_tile ingest supports up to 256 fill blocks

typedef __attribute__((ext_vector_type(8))) short short8;
typedef __attribute__((ext_vector_type(4))) float f32x4;

__device__ inline short f2bf(float f) {
    unsigned u = __float_as_uint(f);
    return (short)((u + 0x7fffu + ((u >> 16) & 1u)) >> 16);
}

// Build augmented bf16 weight Wa[144][128]:
//   rows 0..127  = W (cast)
//   rows 128+h   = wl[h,:] = sum_c attl[h,c] * W[h*32+c,:]
//   rows 132+h   = wr[h,:]
//   rows 136..143 = 0
__global__ __launch_bounds__(256) void k_prep(const float* __restrict__ W,
                                              const float* __restrict__ attl,
                                              const float* __restrict__ attr,
                                              short* __restrict__ Wa) {
    int blk = blockIdx.x;
    int t = threadIdx.x;
    if (blk < 64) {
        int i = blk * 256 + t;
        Wa[i] = f2bf(W[i]);
    } else if (blk == 64) {
        for (int s = t; s < 1024; s += 256) {
            int which = s >> 9;          // 0 = l, 1 = r
            int h = (s >> 7) & 3;
            int k = s & 127;
            const float* att = which ? attr : attl;
            float acc = 0.f;
#pragma unroll 8
            for (int c = 0; c < 32; ++c)
                acc += att[h * 32 + c] * W[(h * 32 + c) * 128 + k];
            Wa[(128 + which * 4 + h) * 128 + k] = f2bf(acc);
        }
    } else {
        int i = (blk - 65) * 256 + t;    // 1024 zero shorts (rows 136..143)
        if (i < 1024) Wa[136 * 128 + i] = 0;
    }
}

// Per-block counting sort of 8192 edges by row-bucket. No global atomics.
__global__ __launch_bounds__(512) void k_fill(const int* __restrict__ ei,
                                              unsigned int* __restrict__ slab,
                                              int* __restrict__ starts,
                                              int E, int NB) {
    __shared__ int s_hist[NB_PAD];            // counts -> exclusive bases (8 KB)
    __shared__ int s_cur[NB_PAD];             // scatter cursors (8 KB)
    __shared__ unsigned int s_stage[EPB];     // 32 KB
    __shared__ int s_wsum[8];

    int fb = blockIdx.x;
    int t = threadIdx.x;
    int lane = t & 63, wv = t >> 6;
    int e0 = fb * EPB;
    int ecnt = min(EPB, E - e0);
    bool full = (ecnt == EPB) && ((E & 3) == 0);

    for (int i = t; i < NB_PAD; i += 512) s_hist[i] = 0;
    __syncthreads();

    const int* rows = ei;
    const int* cols = ei + E;

    if (full) {
        const int4* r4 = (const int4*)rows + (e0 >> 2);
#pragma unroll
        for (int k = 0; k < 4; ++k) {
            int4 ra = r4[k * 512 + t];
            atomicAdd(&s_hist[ra.x >> 6], 1);
            atomicAdd(&s_hist[ra.y >> 6], 1);
            atomicAdd(&s_hist[ra.z >> 6], 1);
            atomicAdd(&s_hist[ra.w >> 6], 1);
        }
    } else {
        for (int j = t; j < ecnt; j += 512)
            atomicAdd(&s_hist[rows[e0 + j] >> 6], 1);
    }
    __syncthreads();

    int b0 = t * 4;
    int c0 = s_hist[b0], c1 = s_hist[b0 + 1], c2 = s_hist[b0 + 2], c3 = s_hist[b0 + 3];
    int p = c0 + c1 + c2 + c3;
    int v = p;
#pragma unroll
    for (int off = 1; off < 64; off <<= 1) {
        int u = __shfl_up(v, off);
        if (lane >= off) v += u;
    }
    if (lane == 63) s_wsum[wv] = v;
    __syncthreads();
    if (t == 0) {
        int run = 0;
#pragma unroll
        for (int w = 0; w < 8; ++w) { int tmp = s_wsum[w]; s_wsum[w] = run; run += tmp; }
    }
    __syncthreads();
    int base = s_wsum[wv] + (v - p);
    int e1 = base + c0, e2 = e1 + c1, e3 = e2 + c2;
    s_hist[b0] = base; s_hist[b0 + 1] = e1; s_hist[b0 + 2] = e2; s_hist[b0 + 3] = e3;
    s_cur[b0] = base;  s_cur[b0 + 1] = e1;  s_cur[b0 + 2] = e2;  s_cur[b0 + 3] = e3;
    size_t sb = (size_t)fb * (NB + 1);
    if (b0 + 0 <= NB) starts[sb + b0 + 0] = base;
    if (b0 + 1 <= NB) starts[sb + b0 + 1] = e1;
    if (b0 + 2 <= NB) starts[sb + b0 + 2] = e2;
    if (b0 + 3 <= NB) starts[sb + b0 + 3] = e3;
    __syncthreads();

    if (full) {
        const int4* r4 = (const int4*)rows + (e0 >> 2);
        const int4* c4 = (const int4*)cols + (e0 >> 2);
#pragma unroll
        for (int k = 0; k < 4; ++k) {
            int4 ra = r4[k * 512 + t];
            int4 ca = c4[k * 512 + t];
            int pos;
            pos = atomicAdd(&s_cur[ra.x >> 6], 1);
            s_stage[pos] = ((unsigned int)ca.x << 6) | (unsigned int)(ra.x & 63);
            pos = atomicAdd(&s_cur[ra.y >> 6], 1);
            s_stage[pos] = ((unsigned int)ca.y << 6) | (unsigned int)(ra.y & 63);
            pos = atomicAdd(&s_cur[ra.z >> 6], 1);
            s_stage[pos] = ((unsigned int)ca.z << 6) | (unsigned int)(ra.z & 63);
            pos = atomicAdd(&s_cur[ra.w >> 6], 1);
            s_stage[pos] = ((unsigned int)ca.w << 6) | (unsigned int)(ra.w & 63);
        }
    } else {
        for (int j = t; j < ecnt; j += 512) {
            int rr = rows[e0 + j], cc = cols[e0 + j];
            int pos = atomicAdd(&s_cur[rr >> 6], 1);
            s_stage[pos] = ((unsigned int)cc << 6) | (unsigned int)(rr & 63);
        }
    }
    __syncthreads();

    uint4* dst = (uint4*)(slab + (size_t)fb * EPB);
    const uint4* src = (const uint4*)s_stage;
    int n4 = (ecnt + 3) >> 2;
    for (int i = t; i < n4; i += 512) dst[i] = src[i];
}

// MFMA GEMM: 512 threads = 8 waves, 128 nodes/block, Wa staged in LDS.
__global__ __launch_bounds__(512) void k_gemm(const float* __restrict__ x,
                                              const short* __restrict__ Wa,
                                              __half* __restrict__ xph,
                                              float* __restrict__ l,
                                              float* __restrict__ r,
                                              int N) {
    // 144 rows, row stride 17 short8 (272 B): ds_read_b128 bank floor.
    __shared__ short s_wa[144 * 136];         // 38.25 KB
    int t = threadIdx.x;
    {
        const short8* g = (const short8*)Wa;
        short8* s = (short8*)s_wa;
        for (int i = t; i < 144 * 16; i += 512) {
            int row = i >> 4, k8 = i & 15;
            s[row * 17 + k8] = g[i];
        }
    }
    __syncthreads();

    int wave = t >> 6, lane = t & 63;
    int li = lane & 15, quad = lane >> 4;
    int base = blockIdx.x * 128 + wave * 16;

    f32x4 acc[9];
#pragma unroll
    for (int nt = 0; nt < 9; ++nt) acc[nt] = (f32x4){0.f, 0.f, 0.f, 0.f};

    int anode = base + li;
    bool avalid = anode < N;
    const float4* x4 = (const float4*)x;
    const short8* wb8 = (const short8*)s_wa;

#pragma unroll
    for (int kc = 0; kc < 4; ++kc) {
        float4 p0 = make_float4(0.f, 0.f, 0.f, 0.f), p1 = p0;
        if (avalid) {
            p0 = x4[(size_t)anode * 32 + kc * 8 + quad * 2];
            p1 = x4[(size_t)anode * 32 + kc * 8 + quad * 2 + 1];
        }
        short8 a;
        a[0] = f2bf(p0.x); a[1] = f2bf(p0.y); a[2] = f2bf(p0.z); a[3] = f2bf(p0.w);
        a[4] = f2bf(p1.x); a[5] = f2bf(p1.y); a[6] = f2bf(p1.z); a[7] = f2bf(p1.w);
#pragma unroll
        for (int nt = 0; nt < 9; ++nt) {
            short8 b = wb8[(nt * 16 + li) * 17 + kc * 4 + quad];
            acc[nt] = __builtin_amdgcn_mfma_f32_16x16x32_bf16(a, b, acc[nt], 0, 0, 0);
        }
    }

#pragma unroll
    for (int j = 0; j < 4; ++j) {
        int node = base + quad * 4 + j;
        if (node >= N) continue;
#pragma unroll
        for (int nt = 0; nt < 8; ++nt)
            xph[(size_t)node * 128 + nt * 16 + li] = __float2half(acc[nt][j]);
        if (li < 4)      l[node * 4 + li] = acc[8][j];
        else if (li < 8) r[node * 4 + li - 4] = acc[8][j];
    }
}

// One block per bucket, 512 threads = 8 waves.
__global__ __launch_bounds__(512) void k_tile(const int* __restrict__ starts,
                                              const unsigned int* __restrict__ slab,
                                              const float* __restrict__ l,
                                              const float* __restrict__ r,
                                              const __half* __restrict__ xph,
                                              const float* __restrict__ bias,
                                              float* __restrict__ out,
                                              int N, int NB, int FB) {
    __shared__ unsigned int s_packed[SLAB];   // 8 KB
    __shared__ int s_col[SLAB];               // 8 KB
    __shared__ __half s_w[SLAB * 4];          // 16 KB: [pos][h]
    __shared__ float s_dsum[TILE_ROWS * 4];   // 1 KB, exact per-(row,head) denom
    __shared__ float s_l[TILE_ROWS * 4];      // 1 KB
    __shared__ int s_start[TILE_ROWS + 1];
    __shared__ int s_cursor[TILE_ROWS];
    __shared__ int s_cnt[TILE_ROWS];
    __shared__ int s_fbase[FBMAX];
    __shared__ int s_foff[FBMAX + 1];
    __shared__ int s_w4[4];

    int b = blockIdx.x;
    int base = b * TILE_ROWS;
    int t = threadIdx.x;
    int lane = t & 63, wv = t >> 6;
    int rows = min(TILE_ROWS, N - base);

    if (t < TILE_ROWS) s_cnt[t] = 0;
    if (t < TILE_ROWS * 4) s_dsum[t] = 0.f;
    if (t < rows * 4) s_l[t] = l[base * 4 + t];

    // per-fill-block run start/count for this bucket
    int myc = 0;
    if (t < FB) {
        const int* sp = starts + (size_t)t * (NB + 1) + b;
        int a0 = sp[0], a1 = sp[1];
        s_fbase[t] = a0;
        myc = a1 - a0;
    }
    int v = 0;
    if (t < 256) {
        v = myc;
#pragma unroll
        for (int off = 1; off < 64; off <<= 1) {
            int u = __shfl_up(v, off);
            if (lane >= off) v += u;
        }
        if (lane == 63) s_w4[wv] = v;
    }
    __syncthreads();
    if (t == 0) {
        int run = 0;
#pragma unroll
        for (int w = 0; w < 4; ++w) { int tmp = s_w4[w]; s_w4[w] = run; run += tmp; }
        s_foff[0] = 0;
    }
    __syncthreads();
    if (t < 256) s_foff[t + 1] = v + s_w4[wv];
    __syncthreads();
    int tot = s_foff[FB];
    if (tot > SLAB) tot = SLAB;

    // gather runs into s_packed (binary search for owning fill block)
    for (int i = t; i < tot; i += 512) {
        int lo = 0, hi = FB;
        while (hi - lo > 1) {
            int mid = (lo + hi) >> 1;
            if (s_foff[mid] <= i) lo = mid; else hi = mid;
        }
        unsigned int p = slab[(size_t)lo * EPB + s_fbase[lo] + (i - s_foff[lo])];
        s_packed[i] = p;
        atomicAdd(&s_cnt[p & 63], 1);
    }
    __syncthreads();

    // counting-sort prefix per row
    if (t < 64) {
        int c = s_cnt[t];
        int vv = c;
#pragma unroll
        for (int off = 1; off < 64; off <<= 1) {
            int u = __shfl_up(vv, off);
            if (t >= off) vv += u;
        }
        s_start[t + 1] = vv;
        if (t == 0) s_start[0] = 0;
        s_cursor[t] = vv - c;
    }
    __syncthreads();

    // scatter + alpha: one float4 r read per edge, 4 head weights -> fp16 LDS,
    // exact per-(row,head) denominators via LDS atomics.
    for (int i = t; i < tot; i += 512) {
        unsigned int p = s_packed[i];
        int row = (int)(p & 63);
        int col = (int)(p >> 6);
        int pos = atomicAdd(&s_cursor[row], 1);
        s_col[pos] = col;
        float4 rv = ((const float4*)r)[col];
        float4 lv = ((const float4*)s_l)[row];
        float w0 = lv.x + rv.x, w1 = lv.y + rv.y;
        float w2 = lv.z + rv.z, w3 = lv.w + rv.w;
        w0 = w0 >= 0.f ? w0 : NEG_SLOPE * w0;
        w1 = w1 >= 0.f ? w1 : NEG_SLOPE * w1;
        w2 = w2 >= 0.f ? w2 : NEG_SLOPE * w2;
        w3 = w3 >= 0.f ? w3 : NEG_SLOPE * w3;
        w0 = __expf(w0); w1 = __expf(w1); w2 = __expf(w2); w3 = __expf(w3);
        ((__half2*)s_w)[pos * 2]     = __floats2half2_rn(w0, w1);
        ((__half2*)s_w)[pos * 2 + 1] = __floats2half2_rn(w2, w3);
        atomicAdd(&s_dsum[row * 4 + 0], w0);
        atomicAdd(&s_dsum[row * 4 + 1], w1);
        atomicAdd(&s_dsum[row * 4 + 2], w2);
        atomicAdd(&s_dsum[row * 4 + 3], w3);
    }
    __syncthreads();

    int quarter = lane >> 4;   // edge slot within wave (4 in flight)
    int li = lane & 15;        // channel block: fp16 chans 8li..8li+7
    int h = li >> 2;           // head of this channel block
    const float4* xp4g = (const float4*)xph;  // 16B = 8 halves

    float4 b0 = ((const float4*)bias)[2 * li];
    float4 b1 = ((const float4*)bias)[2 * li + 1];

    for (int rl = wv; rl < rows; rl += 8) {
        int s0 = s_start[rl], s1 = s_start[rl + 1];
        float a0 = 0.f, a1 = 0.f, a2 = 0.f, a3 = 0.f;
        float a4 = 0.f, a5 = 0.f, a6 = 0.f, a7 = 0.f;
        // 2-deep pipelined gather: both loads issue before either use.
        for (int i = s0 + quarter; i < s1; i += 8) {
            int iB = i + 4;
            bool hB = iB < s1;
            int colA = s_col[i];
            float wA = __half2float(s_w[i * 4 + h]);
            int colB = hB ? s_col[iB] : colA;
            float wB = hB ? __half2float(s_w[iB * 4 + h]) : 0.f;
            float4 rawA = xp4g[(size_t)colA * 16 + li];
            float4 rawB = xp4g[(size_t)colB * 16 + li];
            {
                __half2* hp = (__half2*)&rawA;
                float2 f0 = __half22float2(hp[0]);
                float2 f1 = __half22float2(hp[1]);
                float2 f2 = __half22float2(hp[2]);
                float2 f3 = __half22float2(hp[3]);
                a0 += wA * f0.x; a1 += wA * f0.y;
                a2 += wA * f1.x; a3 += wA * f1.y;
                a4 += wA * f2.x; a5 += wA * f2.y;
                a6 += wA * f3.x; a7 += wA * f3.y;
            }
            {
                __half2* hp = (__half2*)&rawB;
                float2 f0 = __half22float2(hp[0]);
                float2 f1 = __half22float2(hp[1]);
                float2 f2 = __half22float2(hp[2]);
                float2 f3 = __half22float2(hp[3]);
                a0 += wB * f0.x; a1 += wB * f0.y;
                a2 += wB * f1.x; a3 += wB * f1.y;
                a4 += wB * f2.x; a5 += wB * f2.y;
                a6 += wB * f3.x; a7 += wB * f3.y;
            }
        }
        a0 += __shfl_xor(a0, 16); a0 += __shfl_xor(a0, 32);
        a1 += __shfl_xor(a1, 16); a1 += __shfl_xor(a1, 32);
        a2 += __shfl_xor(a2, 16); a2 += __shfl_xor(a2, 32);
        a3 += __shfl_xor(a3, 16); a3 += __shfl_xor(a3, 32);
        a4 += __shfl_xor(a4, 16); a4 += __shfl_xor(a4, 32);
        a5 += __shfl_xor(a5, 16); a5 += __shfl_xor(a5, 32);
        a6 += __shfl_xor(a6, 16); a6 += __shfl_xor(a6, 32);
        a7 += __shfl_xor(a7, 16); a7 += __shfl_xor(a7, 32);
        if (quarter == 0) {
            float inv = 1.f / (s_dsum[rl * 4 + h] + 1e-16f);
            float4 o0, o1;
            o0.x = a0 * inv + b0.x; o0.y = a1 * inv + b0.y;
            o0.z = a2 * inv + b0.z; o0.w = a3 * inv + b0.w;
            o1.x = a4 * inv + b1.x; o1.y = a5 * inv + b1.y;
            o1.z = a6 * inv + b1.z; o1.w = a7 * inv + b1.w;
            ((float4*)out)[(size_t)(base + rl) * 32 + 2 * li] = o0;
            ((float4*)out)[(size_t)(base + rl) * 32 + 2 * li + 1] = o1;
        }
    }
}

extern "C" void kernel_launch(void* const* d_in, const int* in_sizes, int n_in,
                              void* d_out, int out_size, void* d_ws, size_t ws_size,
                              hipStream_t stream) {
    const float* x    = (const float*)d_in[0];
    const int*   ei   = (const int*)d_in[1];
    const float* W    = (const float*)d_in[2];
    const float* attl = (const float*)d_in[3];
    const float* attr = (const float*)d_in[4];
    const float* bias = (const float*)d_in[5];
    int N = in_sizes[0] / 128;
    int E = in_sizes[1] / 2;
    int NB = (N + TILE_ROWS - 1) / TILE_ROWS;
    int FB = (E + EPB - 1) / EPB;    // 196 for E=1.6M (k_tile supports <= FBMAX)

    char* ws = (char*)d_ws;
    __half* xph = (__half*)ws;   ws += (size_t)N * 128 * 2;          // 25.6 MB
    float* l    = (float*)ws;    ws += (size_t)N * 4 * 4;
    float* r    = (float*)ws;    ws += (size_t)N * 4 * 4;
    short* Wa   = (short*)ws;    ws += 144 * 128 * 2;
    int* starts = (int*)ws;      ws += (size_t)FB * (NB + 1) * 4;    // 1.23 MB
    unsigned int* slab = (unsigned int*)ws; ws += (size_t)FB * EPB * 4; // 6.42 MB

    float* out = (float*)d_out;
    int GB = (N + 127) / 128;

    k_prep<<<69, 256, 0, stream>>>(W, attl, attr, Wa);
    k_fill<<<FB, 512, 0, stream>>>(ei, slab, starts, E, NB);
    k_gemm<<<GB, 512, 0, stream>>>(x, Wa, xph, l, r, N);
    k_tile<<<NB, 512, 0, stream>>>(starts, slab, l, r, xph, bias, out, N, NB, FB);
}

// Round 3
// 204.462 us; speedup vs baseline: 1.3001x; 1.0984x over previous
//
#include <hip/hip_runtime.h>
#include <hip/hip_fp16.h>

// GAT conv: N=100000, E=1.6M, IN_C=128, OUT_C=32, HEADS=4 (OC=128)
// Round 10:
//  - k_tile scatter fixed (round 9 regression post-mortem: dsum LDS atomics
//    serialized ~16-way same-address, r-gather had no ILP between barriers;
//    bank conflicts doubled 377K->734K, stall time +26us):
//      * denominators now computed atomic-free in a dedicated pass over the
//        row-sorted s_w (256 threads, one per (row,head), ~16 serial reads).
//        Also makes num/denom numerically consistent (both fp16 w).
//      * scatter pass unrolled to its exact 4 slots/thread with all 4
//        r[col] float4 gathers issued before any atomic/exp/store.
//  - k_gemm epilogue: C re-staged through the s_wa LDS region (free union)
//    and written as coalesced short8 (was 12.8M scalar 2B stores = ~20us of
//    store issue).
//  - fill+gemm re-fused with role split on blockIdx (independent work,
//    complementary pipes: fill is a 196-block latency kernel leaving CUs
//    idle, gemm is streaming). LDS union 48KB -> 3 blocks/CU.

constexpr float NEG_SLOPE = 0.2f;
constexpr int TILE_ROWS = 64;       // rows per bucket (row>>6)
constexpr int SLAB = 2048;          // max edges per bucket staged in LDS
constexpr int EPB = 8192;           // edges per fill block
constexpr int NB_PAD = 2048;        // padded bucket count for block scan
constexpr int FBMAX = 256;          // k_tile ingest supports up to 256 fill blocks

typedef __attribute__((ext_vector_type(8))) short short8;
typedef __attribute__((ext_vector_type(4))) float f32x4;

__device__ inline short f2bf(float f) {
    unsigned u = __float_as_uint(f);
    return (short)((u + 0x7fffu + ((u >> 16) & 1u)) >> 16);
}

// Build augmented bf16 weight Wa[144][128]:
//   rows 0..127  = W (cast)
//   rows 128+h   = wl[h,:] = sum_c attl[h,c] * W[h*32+c,:]
//   rows 132+h   = wr[h,:]
//   rows 136..143 = 0
__global__ __launch_bounds__(256) void k_prep(const float* __restrict__ W,
                                              const float* __restrict__ attl,
                                              const float* __restrict__ attr,
                                              short* __restrict__ Wa) {
    int blk = blockIdx.x;
    int t = threadIdx.x;
    if (blk < 64) {
        int i = blk * 256 + t;
        Wa[i] = f2bf(W[i]);
    } else if (blk == 64) {
        for (int s = t; s < 1024; s += 256) {
            int which = s >> 9;          // 0 = l, 1 = r
            int h = (s >> 7) & 3;
            int k = s & 127;
            const float* att = which ? attr : attl;
            float acc = 0.f;
#pragma unroll 8
            for (int c = 0; c < 32; ++c)
                acc += att[h * 32 + c] * W[(h * 32 + c) * 128 + k];
            Wa[(128 + which * 4 + h) * 128 + k] = f2bf(acc);
        }
    } else {
        int i = (blk - 65) * 256 + t;    // 1024 zero shorts (rows 136..143)
        if (i < 1024) Wa[136 * 128 + i] = 0;
    }
}

// Fused fill (blocks [0,FB)) + gemm (blocks [FB,FB+GB)).
// fill: per-block deterministic counting sort of 8192 edges, no global atomics.
// gemm: MFMA 128 nodes/block, Wa staged in LDS, C re-staged for coalesced out.
__global__ __launch_bounds__(512) void k_fg(const float* __restrict__ x,
                                            const short* __restrict__ Wa,
                                            const int* __restrict__ ei,
                                            __half* __restrict__ xph,
                                            float* __restrict__ l,
                                            float* __restrict__ r,
                                            unsigned int* __restrict__ slab,
                                            int* __restrict__ starts,
                                            int N, int E, int NB, int FB) {
    __shared__ __align__(16) char smem[49152];   // union: fill 48KB / gemm 38.25KB
    __shared__ int s_wsum[8];
    int t = threadIdx.x;
    int lane = t & 63, wv = t >> 6;

    if ((int)blockIdx.x < FB) {
        // ------------------------- fill role -------------------------
        int* s_hist = (int*)smem;                       // 8 KB
        int* s_cur  = (int*)(smem + 8192);              // 8 KB
        unsigned int* s_stage = (unsigned int*)(smem + 16384); // 32 KB

        int fb = blockIdx.x;
        int e0 = fb * EPB;
        int ecnt = min(EPB, E - e0);
        bool full = (ecnt == EPB) && ((E & 3) == 0);

        for (int i = t; i < NB_PAD; i += 512) s_hist[i] = 0;
        __syncthreads();

        const int* rows = ei;
        const int* cols = ei + E;

        if (full) {
            const int4* r4 = (const int4*)rows + (e0 >> 2);
#pragma unroll
            for (int k = 0; k < 4; ++k) {
                int4 ra = r4[k * 512 + t];
                atomicAdd(&s_hist[ra.x >> 6], 1);
                atomicAdd(&s_hist[ra.y >> 6], 1);
                atomicAdd(&s_hist[ra.z >> 6], 1);
                atomicAdd(&s_hist[ra.w >> 6], 1);
            }
        } else {
            for (int j = t; j < ecnt; j += 512)
                atomicAdd(&s_hist[rows[e0 + j] >> 6], 1);
        }
        __syncthreads();

        int b0 = t * 4;
        int c0 = s_hist[b0], c1 = s_hist[b0 + 1], c2 = s_hist[b0 + 2], c3 = s_hist[b0 + 3];
        int p = c0 + c1 + c2 + c3;
        int v = p;
#pragma unroll
        for (int off = 1; off < 64; off <<= 1) {
            int u = __shfl_up(v, off);
            if (lane >= off) v += u;
        }
        if (lane == 63) s_wsum[wv] = v;
        __syncthreads();
        if (t == 0) {
            int run = 0;
#pragma unroll
            for (int w = 0; w < 8; ++w) { int tmp = s_wsum[w]; s_wsum[w] = run; run += tmp; }
        }
        __syncthreads();
        int base = s_wsum[wv] + (v - p);
        int e1 = base + c0, e2 = e1 + c1, e3 = e2 + c2;
        s_hist[b0] = base; s_hist[b0 + 1] = e1; s_hist[b0 + 2] = e2; s_hist[b0 + 3] = e3;
        s_cur[b0] = base;  s_cur[b0 + 1] = e1;  s_cur[b0 + 2] = e2;  s_cur[b0 + 3] = e3;
        size_t sb = (size_t)fb * (NB + 1);
        if (b0 + 0 <= NB) starts[sb + b0 + 0] = base;
        if (b0 + 1 <= NB) starts[sb + b0 + 1] = e1;
        if (b0 + 2 <= NB) starts[sb + b0 + 2] = e2;
        if (b0 + 3 <= NB) starts[sb + b0 + 3] = e3;
        __syncthreads();

        if (full) {
            const int4* r4 = (const int4*)rows + (e0 >> 2);
            const int4* c4 = (const int4*)cols + (e0 >> 2);
#pragma unroll
            for (int k = 0; k < 4; ++k) {
                int4 ra = r4[k * 512 + t];
                int4 ca = c4[k * 512 + t];
                int pos;
                pos = atomicAdd(&s_cur[ra.x >> 6], 1);
                s_stage[pos] = ((unsigned int)ca.x << 6) | (unsigned int)(ra.x & 63);
                pos = atomicAdd(&s_cur[ra.y >> 6], 1);
                s_stage[pos] = ((unsigned int)ca.y << 6) | (unsigned int)(ra.y & 63);
                pos = atomicAdd(&s_cur[ra.z >> 6], 1);
                s_stage[pos] = ((unsigned int)ca.z << 6) | (unsigned int)(ra.z & 63);
                pos = atomicAdd(&s_cur[ra.w >> 6], 1);
                s_stage[pos] = ((unsigned int)ca.w << 6) | (unsigned int)(ra.w & 63);
            }
        } else {
            for (int j = t; j < ecnt; j += 512) {
                int rr = rows[e0 + j], cc = cols[e0 + j];
                int pos = atomicAdd(&s_cur[rr >> 6], 1);
                s_stage[pos] = ((unsigned int)cc << 6) | (unsigned int)(rr & 63);
            }
        }
        __syncthreads();

        uint4* dst = (uint4*)(slab + (size_t)fb * EPB);
        const uint4* src = (const uint4*)s_stage;
        int n4 = (ecnt + 3) >> 2;
        for (int i = t; i < n4; i += 512) dst[i] = src[i];
        return;
    }

    // ------------------------- gemm role -------------------------
    short* s_wa = (short*)smem;     // 144 rows x 136 shorts (272B stride)
    {
        const short8* g = (const short8*)Wa;
        short8* s = (short8*)s_wa;
        for (int i = t; i < 144 * 16; i += 512) {
            int row = i >> 4, k8 = i & 15;
            s[row * 17 + k8] = g[i];
        }
    }
    __syncthreads();

    int li = lane & 15, quad = lane >> 4;
    int gb = blockIdx.x - FB;
    int base = gb * 128 + wv * 16;

    f32x4 acc[9];
#pragma unroll
    for (int nt = 0; nt < 9; ++nt) acc[nt] = (f32x4){0.f, 0.f, 0.f, 0.f};

    int anode = base + li;
    bool avalid = anode < N;
    const float4* x4 = (const float4*)x;
    const short8* wb8 = (const short8*)s_wa;

#pragma unroll
    for (int kc = 0; kc < 4; ++kc) {
        float4 p0 = make_float4(0.f, 0.f, 0.f, 0.f), p1 = p0;
        if (avalid) {
            p0 = x4[(size_t)anode * 32 + kc * 8 + quad * 2];
            p1 = x4[(size_t)anode * 32 + kc * 8 + quad * 2 + 1];
        }
        short8 a;
        a[0] = f2bf(p0.x); a[1] = f2bf(p0.y); a[2] = f2bf(p0.z); a[3] = f2bf(p0.w);
        a[4] = f2bf(p1.x); a[5] = f2bf(p1.y); a[6] = f2bf(p1.z); a[7] = f2bf(p1.w);
#pragma unroll
        for (int nt = 0; nt < 9; ++nt) {
            short8 b = wb8[(nt * 16 + li) * 17 + kc * 4 + quad];
            acc[nt] = __builtin_amdgcn_mfma_f32_16x16x32_bf16(a, b, acc[nt], 0, 0, 0);
        }
    }

    // l/r columns straight to global
#pragma unroll
    for (int j = 0; j < 4; ++j) {
        int node = base + quad * 4 + j;
        if (node >= N) continue;
        if (li < 4)      l[node * 4 + li] = acc[8][j];
        else if (li < 8) r[node * 4 + li - 4] = acc[8][j];
    }

    // re-stage C through s_wa (all reads of Wa are done), then coalesced out
    __syncthreads();
    __half* s_out = (__half*)s_wa;   // [128 nodes][136] halves, stride 272B
#pragma unroll
    for (int j = 0; j < 4; ++j) {
        int nl = wv * 16 + quad * 4 + j;
#pragma unroll
        for (int nt = 0; nt < 8; ++nt)
            s_out[nl * 136 + nt * 16 + li] = __float2half(acc[nt][j]);
    }
    __syncthreads();
    {
        int nl = t >> 2, seg = t & 3;
        int node = gb * 128 + nl;
        if (node < N) {
            const short8* sr = (const short8*)s_wa;
            short8* xp8 = (short8*)xph;
#pragma unroll
            for (int q = 0; q < 4; ++q)
                xp8[(size_t)node * 16 + seg * 4 + q] = sr[nl * 17 + seg * 4 + q];
        }
    }
}

// One block per bucket, 512 threads = 8 waves.
__global__ __launch_bounds__(512) void k_tile(const int* __restrict__ starts,
                                              const unsigned int* __restrict__ slab,
                                              const float* __restrict__ l,
                                              const float* __restrict__ r,
                                              const __half* __restrict__ xph,
                                              const float* __restrict__ bias,
                                              float* __restrict__ out,
                                              int N, int NB, int FB) {
    __shared__ unsigned int s_packed[SLAB];   // 8 KB
    __shared__ int s_col[SLAB];               // 8 KB
    __shared__ __half s_w[SLAB * 4];          // 16 KB: [pos][h]
    __shared__ float s_dsum[TILE_ROWS * 4];   // 1 KB
    __shared__ float s_l[TILE_ROWS * 4];      // 1 KB
    __shared__ int s_start[TILE_ROWS + 1];
    __shared__ int s_cursor[TILE_ROWS];
    __shared__ int s_cnt[TILE_ROWS];
    __shared__ int s_fbase[FBMAX];
    __shared__ int s_foff[FBMAX + 1];
    __shared__ int s_w4[4];

    int b = blockIdx.x;
    int base = b * TILE_ROWS;
    int t = threadIdx.x;
    int lane = t & 63, wv = t >> 6;
    int rows = min(TILE_ROWS, N - base);

    if (t < TILE_ROWS) s_cnt[t] = 0;
    if (t < rows * 4) s_l[t] = l[base * 4 + t];

    // per-fill-block run start/count for this bucket
    int myc = 0;
    if (t < FB) {
        const int* sp = starts + (size_t)t * (NB + 1) + b;
        int a0 = sp[0], a1 = sp[1];
        s_fbase[t] = a0;
        myc = a1 - a0;
    }
    int v = 0;
    if (t < 256) {
        v = myc;
#pragma unroll
        for (int off = 1; off < 64; off <<= 1) {
            int u = __shfl_up(v, off);
            if (lane >= off) v += u;
        }
        if (lane == 63) s_w4[wv] = v;
    }
    __syncthreads();
    if (t == 0) {
        int run = 0;
#pragma unroll
        for (int w = 0; w < 4; ++w) { int tmp = s_w4[w]; s_w4[w] = run; run += tmp; }
        s_foff[0] = 0;
    }
    __syncthreads();
    if (t < 256) s_foff[t + 1] = v + s_w4[wv];
    __syncthreads();
    int tot = s_foff[FB];
    if (tot > SLAB) tot = SLAB;

    // gather runs into s_packed (binary search for owning fill block)
    for (int i = t; i < tot; i += 512) {
        int lo = 0, hi = FB;
        while (hi - lo > 1) {
            int mid = (lo + hi) >> 1;
            if (s_foff[mid] <= i) lo = mid; else hi = mid;
        }
        unsigned int p = slab[(size_t)lo * EPB + s_fbase[lo] + (i - s_foff[lo])];
        s_packed[i] = p;
        atomicAdd(&s_cnt[p & 63], 1);
    }
    __syncthreads();

    // counting-sort prefix per row
    if (t < 64) {
        int c = s_cnt[t];
        int vv = c;
#pragma unroll
        for (int off = 1; off < 64; off <<= 1) {
            int u = __shfl_up(vv, off);
            if (t >= off) vv += u;
        }
        s_start[t + 1] = vv;
        if (t == 0) s_start[0] = 0;
        s_cursor[t] = vv - c;
    }
    __syncthreads();

    // scatter + alpha. Exactly <=4 slots per thread (SLAB=2048, 512 threads):
    // read all slots, issue all 4 r gathers, THEN atomics/exp/stores.
    {
        int row_[4], col_[4];
        bool val_[4];
#pragma unroll
        for (int s = 0; s < 4; ++s) {
            int i = t + s * 512;
            bool valid = i < tot;
            unsigned int p = valid ? s_packed[i] : 0u;
            row_[s] = (int)(p & 63);
            col_[s] = valid ? (int)(p >> 6) : 0;
            val_[s] = valid;
        }
        float4 rv0 = ((const float4*)r)[col_[0]];
        float4 rv1 = ((const float4*)r)[col_[1]];
        float4 rv2 = ((const float4*)r)[col_[2]];
        float4 rv3 = ((const float4*)r)[col_[3]];
#pragma unroll
        for (int s = 0; s < 4; ++s) {
            if (!val_[s]) continue;
            float4 rv = s == 0 ? rv0 : s == 1 ? rv1 : s == 2 ? rv2 : rv3;
            int row = row_[s];
            int pos = atomicAdd(&s_cursor[row], 1);
            s_col[pos] = col_[s];
            float4 lv = ((const float4*)s_l)[row];
            float w0 = lv.x + rv.x, w1 = lv.y + rv.y;
            float w2 = lv.z + rv.z, w3 = lv.w + rv.w;
            w0 = w0 >= 0.f ? w0 : NEG_SLOPE * w0;
            w1 = w1 >= 0.f ? w1 : NEG_SLOPE * w1;
            w2 = w2 >= 0.f ? w2 : NEG_SLOPE * w2;
            w3 = w3 >= 0.f ? w3 : NEG_SLOPE * w3;
            w0 = __expf(w0); w1 = __expf(w1); w2 = __expf(w2); w3 = __expf(w3);
            ((__half2*)s_w)[pos * 2]     = __floats2half2_rn(w0, w1);
            ((__half2*)s_w)[pos * 2 + 1] = __floats2half2_rn(w2, w3);
        }
    }
    __syncthreads();

    // atomic-free denominators over the row-sorted s_w: thread = (row, head)
    if (t < 256) {
        int row = t >> 2, h = t & 3;
        if (row < rows) {
            int s0 = s_start[row], s1 = s_start[row + 1];
            float d = 0.f;
            for (int i = s0; i < s1; ++i)
                d += __half2float(s_w[i * 4 + h]);
            s_dsum[t] = d;
        }
    }
    __syncthreads();

    int quarter = lane >> 4;   // edge slot within wave (4 in flight)
    int li = lane & 15;        // channel block: fp16 chans 8li..8li+7
    int h = li >> 2;           // head of this channel block
    const float4* xp4g = (const float4*)xph;  // 16B = 8 halves

    float4 b0 = ((const float4*)bias)[2 * li];
    float4 b1 = ((const float4*)bias)[2 * li + 1];

    for (int rl = wv; rl < rows; rl += 8) {
        int s0 = s_start[rl], s1 = s_start[rl + 1];
        float a0 = 0.f, a1 = 0.f, a2 = 0.f, a3 = 0.f;
        float a4 = 0.f, a5 = 0.f, a6 = 0.f, a7 = 0.f;
        // 2-deep pipelined gather: both loads issue before either use.
        for (int i = s0 + quarter; i < s1; i += 8) {
            int iB = i + 4;
            bool hB = iB < s1;
            int colA = s_col[i];
            float wA = __half2float(s_w[i * 4 + h]);
            int colB = hB ? s_col[iB] : colA;
            float wB = hB ? __half2float(s_w[iB * 4 + h]) : 0.f;
            float4 rawA = xp4g[(size_t)colA * 16 + li];
            float4 rawB = xp4g[(size_t)colB * 16 + li];
            {
                __half2* hp = (__half2*)&rawA;
                float2 f0 = __half22float2(hp[0]);
                float2 f1 = __half22float2(hp[1]);
                float2 f2 = __half22float2(hp[2]);
                float2 f3 = __half22float2(hp[3]);
                a0 += wA * f0.x; a1 += wA * f0.y;
                a2 += wA * f1.x; a3 += wA * f1.y;
                a4 += wA * f2.x; a5 += wA * f2.y;
                a6 += wA * f3.x; a7 += wA * f3.y;
            }
            {
                __half2* hp = (__half2*)&rawB;
                float2 f0 = __half22float2(hp[0]);
                float2 f1 = __half22float2(hp[1]);
                float2 f2 = __half22float2(hp[2]);
                float2 f3 = __half22float2(hp[3]);
                a0 += wB * f0.x; a1 += wB * f0.y;
                a2 += wB * f1.x; a3 += wB * f1.y;
                a4 += wB * f2.x; a5 += wB * f2.y;
                a6 += wB * f3.x; a7 += wB * f3.y;
            }
        }
        a0 += __shfl_xor(a0, 16); a0 += __shfl_xor(a0, 32);
        a1 += __shfl_xor(a1, 16); a1 += __shfl_xor(a1, 32);
        a2 += __shfl_xor(a2, 16); a2 += __shfl_xor(a2, 32);
        a3 += __shfl_xor(a3, 16); a3 += __shfl_xor(a3, 32);
        a4 += __shfl_xor(a4, 16); a4 += __shfl_xor(a4, 32);
        a5 += __shfl_xor(a5, 16); a5 += __shfl_xor(a5, 32);
        a6 += __shfl_xor(a6, 16); a6 += __shfl_xor(a6, 32);
        a7 += __shfl_xor(a7, 16); a7 += __shfl_xor(a7, 32);
        if (quarter == 0) {
            float inv = 1.f / (s_dsum[rl * 4 + h] + 1e-16f);
            float4 o0, o1;
            o0.x = a0 * inv + b0.x; o0.y = a1 * inv + b0.y;
            o0.z = a2 * inv + b0.z; o0.w = a3 * inv + b0.w;
            o1.x = a4 * inv + b1.x; o1.y = a5 * inv + b1.y;
            o1.z = a6 * inv + b1.z; o1.w = a7 * inv + b1.w;
            ((float4*)out)[(size_t)(base + rl) * 32 + 2 * li] = o0;
            ((float4*)out)[(size_t)(base + rl) * 32 + 2 * li + 1] = o1;
        }
    }
}

extern "C" void kernel_launch(void* const* d_in, const int* in_sizes, int n_in,
                              void* d_out, int out_size, void* d_ws, size_t ws_size,
                              hipStream_t stream) {
    const float* x    = (const float*)d_in[0];
    const int*   ei   = (const int*)d_in[1];
    const float* W    = (const float*)d_in[2];
    const float* attl = (const float*)d_in[3];
    const float* attr = (const float*)d_in[4];
    const float* bias = (const float*)d_in[5];
    int N = in_sizes[0] / 128;
    int E = in_sizes[1] / 2;
    int NB = (N + TILE_ROWS - 1) / TILE_ROWS;
    int FB = (E + EPB - 1) / EPB;    // 196 for E=1.6M (k_tile supports <= FBMAX)

    char* ws = (char*)d_ws;
    __half* xph = (__half*)ws;   ws += (size_t)N * 128 * 2;          // 25.6 MB
    float* l    = (float*)ws;    ws += (size_t)N * 4 * 4;
    float* r    = (float*)ws;    ws += (size_t)N * 4 * 4;
    short* Wa   = (short*)ws;    ws += 144 * 128 * 2;
    int* starts = (int*)ws;      ws += (size_t)FB * (NB + 1) * 4;    // 1.23 MB
    unsigned int* slab = (unsigned int*)ws; ws += (size_t)FB * EPB * 4; // 6.42 MB

    float* out = (float*)d_out;
    int GB = (N + 127) / 128;

    k_prep<<<69, 256, 0, stream>>>(W, attl, attr, Wa);
    k_fg<<<FB + GB, 512, 0, stream>>>(x, Wa, ei, xph, l, r, slab, starts, N, E, NB, FB);
    k_tile<<<NB, 512, 0, stream>>>(starts, slab, l, r, xph, bias, out, N, NB, FB);
}